// Round 14
// baseline (111.158 us; speedup 1.0000x reference)
//
#include <hip/hip_runtime.h>
#include <math.h>

#define HW 4096
#define KTOT 2304   // 256 * 9

typedef __attribute__((ext_vector_type(8))) short short8v;
typedef __attribute__((ext_vector_type(4))) float float4v;

__device__ __forceinline__ unsigned int bf16rne(float f) {
  unsigned int x = __float_as_uint(f);
  return (x + 0x7fffu + ((x >> 16) & 1u)) >> 16;
}

__device__ __forceinline__ unsigned int bilin_pack(unsigned int u0, unsigned int u1,
                                                   unsigned int u2, unsigned int u3,
                                                   float w0, float w1, float w2, float w3) {
  float lo = w0 * __uint_as_float(u0 << 16) + w1 * __uint_as_float(u1 << 16) +
             w2 * __uint_as_float(u2 << 16) + w3 * __uint_as_float(u3 << 16);
  float hi = w0 * __uint_as_float(u0 & 0xFFFF0000u) + w1 * __uint_as_float(u1 & 0xFFFF0000u) +
             w2 * __uint_as_float(u2 & 0xFFFF0000u) + w3 * __uint_as_float(u3 & 0xFFFF0000u);
  unsigned int r;
  asm("v_cvt_pk_bf16_f32 %0, %1, %2" : "=v"(r) : "v"(lo), "v"(hi));
  return r;
}

// ------------------------------------------------------------------
// ws layout (float offsets):
//   0        : off      [8][4096][18] f32
//   589824   : xT       [8][4096][256] bf16
//   4784128  : wB       [72][16][64][8] bf16
//   5079040  : wOffB    [72][2][64][8] bf16
//   5115904  : part     [256 oc][512] float2
//   5378048  : stats    [256] float2
// ------------------------------------------------------------------

// Merged: blocks [0,512) transpose x -> NHWC bf16 (n = bid&7, XCD-aligned);
// [512,800) pack w_conv frags; [800,836) pack w_offset frags.
__global__ __launch_bounds__(256) void k_tx_prep(const float* __restrict__ x,
                                                 const float* __restrict__ wc,
                                                 const float* __restrict__ wo,
                                                 ushort* __restrict__ xT,
                                                 ushort* __restrict__ wB,
                                                 ushort* __restrict__ wOB) {
  int bid = blockIdx.x;
  if (bid < 512) {
    int n = bid & 7, p0 = (bid >> 3) << 6;
    int t = threadIdx.x;
    int lane = t & 63, wave = t >> 6, c0 = wave << 6;
    const float* xb = x + ((size_t)(n * 256 + c0)) * HW + p0 + lane;
    ushort* ob = xT + ((size_t)n * 4096 + p0 + lane) * 256 + c0;
#pragma unroll
    for (int g = 0; g < 8; ++g) {
      unsigned int u[4];
#pragma unroll
      for (int j = 0; j < 4; ++j) {
        float v0 = xb[(size_t)(g * 8 + 2 * j) * HW];
        float v1 = xb[(size_t)(g * 8 + 2 * j + 1) * HW];
        u[j] = bf16rne(v0) | (bf16rne(v1) << 16);
      }
      *reinterpret_cast<uint4*>(ob + g * 8) = make_uint4(u[0], u[1], u[2], u[3]);
    }
  } else if (bid < 800) {
    int t = (bid - 512) * 256 + threadIdx.x;   // 73728
    int ks = t >> 10;
    int l = t & 63;
    int of = (t >> 6) & 15;
    int kk = ks >> 3;
    int cbase = ((ks & 7) << 5) + ((l >> 4) << 3);
    int oc = (of << 4) + (l & 15);
    unsigned int u[8];
#pragma unroll
    for (int j = 0; j < 8; ++j)
      u[j] = bf16rne(wc[(size_t)oc * KTOT + (size_t)(cbase + j) * 9 + kk]);
    *reinterpret_cast<uint4*>(&wB[(size_t)t * 8]) =
        make_uint4(u[0] | (u[1] << 16), u[2] | (u[3] << 16),
                   u[4] | (u[5] << 16), u[6] | (u[7] << 16));
  } else {
    int t = (bid - 800) * 256 + threadIdx.x;   // 9216
    int ks = t >> 7;
    int l = t & 63;
    int of = (t >> 6) & 1;
    int kk = ks >> 3;
    int cbase = ((ks & 7) << 5) + ((l >> 4) << 3);
    int oc = (of << 4) + (l & 15);
    unsigned int u[8];
#pragma unroll
    for (int j = 0; j < 8; ++j)
      u[j] = (oc < 18) ? bf16rne(wo[(size_t)oc * KTOT + (size_t)(cbase + j) * 9 + kk]) : 0u;
    *reinterpret_cast<uint4*>(&wOB[(size_t)t * 8]) =
        make_uint4(u[0] | (u[1] << 16), u[2] | (u[3] << 16),
                   u[4] | (u[5] << 16), u[6] | (u[7] << 16));
  }
}

// ------------------------------------------------------------------
// Offset conv implicit GEMM — R13-proven k_offset5, unchanged.
// ------------------------------------------------------------------
__global__ __launch_bounds__(512, 4) void k_offset5(
    const ushort* __restrict__ xT, const ushort* __restrict__ wOffB,
    const float* __restrict__ b_off, float* __restrict__ off_out) {
  __shared__ ushort s_tile[2][64 * 64];   // 16 KB

  int bid = blockIdx.x;
  int n = bid & 7, ho = bid >> 3;
  int t = threadIdx.x;
  int lane = t & 63, wave = t >> 6;
  int coct = lane & 7;
  int p = (wave << 3) + (lane >> 3);
  int ocf = wave & 1, pixf = wave >> 1;

  const ushort* xTn = xT + (size_t)n * 4096 * 256;

  float4v acc = (float4v)0.f;

  auto srcp = [&](int kk, const ushort*& s, bool& v) {
    int ky = kk / 3, kx = kk - ky * 3;
    int oy = ho + ky - 1, ox = p + kx - 1;
    v = (oy >= 0) & (oy < 64) & (ox >= 0) & (ox < 64);
    s = xTn + (size_t)(oy * 64 + ox) * 256 + (coct << 3);
  };

  auto issue = [&](uint4& a, const ushort* s, bool v, int cg) {
    a = v ? *reinterpret_cast<const uint4*>(s + (cg << 6)) : make_uint4(0, 0, 0, 0);
  };

  auto step = [&](uint4 a, int ksb, int buf) {
    short8v wf[2];
#pragma unroll
    for (int ks2 = 0; ks2 < 2; ++ks2)
      wf[ks2] = *reinterpret_cast<const short8v*>(
          &wOffB[(((size_t)((ksb + ks2) * 2 + ocf)) * 64 + lane) * 8]);
    *reinterpret_cast<uint4*>(&s_tile[buf][p * 64 + ((coct ^ (p & 7)) << 3)]) = a;
    asm volatile("s_waitcnt lgkmcnt(0)" ::: "memory");
    __builtin_amdgcn_s_barrier();
#pragma unroll
    for (int ks2 = 0; ks2 < 2; ++ks2) {
      int row = (pixf << 4) + (lane & 15);
      int g = (ks2 << 2) + (lane >> 4);
      int slot = g ^ (row & 7);
      short8v vf = *reinterpret_cast<const short8v*>(&s_tile[buf][row * 64 + slot * 8]);
      acc = __builtin_amdgcn_mfma_f32_16x16x32_bf16(wf[ks2], vf, acc, 0, 0, 0);
    }
  };

  const ushort* cs;
  bool cv;
  srcp(0, cs, cv);
  uint4 A, B;
  issue(A, cs, cv, 0);

  for (int kk = 0; kk < 9; ++kk) {
    int ksb = kk << 3;
    issue(B, cs, cv, 1);
    step(A, ksb + 0, 0);
    issue(A, cs, cv, 2);
    step(B, ksb + 2, 1);
    issue(B, cs, cv, 3);
    step(A, ksb + 4, 0);
    const ushort* ns = cs;
    bool nv = cv;
    if (kk < 8) {
      srcp(kk + 1, ns, nv);
      issue(A, ns, nv, 0);
    }
    step(B, ksb + 6, 1);
    cs = ns; cv = nv;
  }

  int pixcol = (pixf << 4) + (lane & 15);
  size_t base = ((size_t)n * 4096 + ho * 64 + pixcol) * 18;
#pragma unroll
  for (int j = 0; j < 4; ++j) {
    int oc = (ocf << 4) + ((lane >> 4) << 2) + j;
    if (oc < 18) off_out[base + oc] = acc[j] + b_off[oc];
  }
}

// ------------------------------------------------------------------
// Deformable conv implicit GEMM — R13 skeleton with SKEWED pipeline:
// per chunk c: [issue taps c+1] [load wf c-1] [pack c -> buf[c&1]]
// [MFMA c-1 from buf[(c-1)&1]] [lgkmcnt(0); barrier].
// ds_write latency hides under MFMA; wf L2 latency hides under pack;
// the drain before barrier waits on long-retired ops. Register-neutral.
// chunk c in [0,36): kk = c>>2, cg = c&3, wf base ks0 = 2c.
// ------------------------------------------------------------------
__global__ __launch_bounds__(512, 4) void k_deform11(
    const ushort* __restrict__ xT, const float* __restrict__ off,
    const ushort* __restrict__ wB, float* __restrict__ out,
    float2* __restrict__ part) {
  __shared__ ushort s_val[2][64 * 64];   // 16 KB
  __shared__ int4   s_gi[9][64];         // 9.2 KB
  __shared__ float4 s_gw[9][64];         // 9.2 KB

  int bid = blockIdx.x;
  int n = bid & 7, ho = bid >> 3;
  int t = threadIdx.x;
  int lane = t & 63, wave = t >> 6;
  int coct = lane & 7;
  int p = (wave << 3) + (lane >> 3);   // 0..63, this thread's pixel

  const ushort* xTn = xT + (size_t)n * 4096 * 256;

  // ---- phase 0: bilinear geometry for all (kk, pix) ----
  for (int e = t; e < 576; e += 512) {
    int pix = e & 63, kk = e >> 6;
    int ky = kk / 3, kx = kk - ky * 3;
    const float* ob = off + ((size_t)n * 4096 + ho * 64 + pix) * 18;
    float dy = ob[2 * kk], dx = ob[2 * kk + 1];
    float py = (float)(ho - 1 + ky) + dy;
    float px = (float)(pix - 1 + kx) + dx;
    float y0f = floorf(py), x0f = floorf(px);
    float ly = py - y0f, lx = px - x0f;
    int y0 = (int)y0f, x0 = (int)x0f;
    int y1 = y0 + 1, x1 = x0 + 1;
    float vy0 = (y0 >= 0 && y0 < 64) ? 1.f : 0.f;
    float vy1 = (y1 >= 0 && y1 < 64) ? 1.f : 0.f;
    float vx0 = (x0 >= 0 && x0 < 64) ? 1.f : 0.f;
    float vx1 = (x1 >= 0 && x1 < 64) ? 1.f : 0.f;
    int cy0 = min(max(y0, 0), 63) << 6, cy1 = min(max(y1, 0), 63) << 6;
    int cx0 = min(max(x0, 0), 63), cx1 = min(max(x1, 0), 63);
    s_gi[kk][pix] = make_int4((cy0 + cx0) << 8, (cy0 + cx1) << 8,
                              (cy1 + cx0) << 8, (cy1 + cx1) << 8);
    s_gw[kk][pix] = make_float4((1.f - ly) * (1.f - lx) * vy0 * vx0,
                                (1.f - ly) * lx * vy0 * vx1,
                                ly * (1.f - lx) * vy1 * vx0,
                                ly * lx * vy1 * vx1);
  }
  __syncthreads();

  float4v acc[2][4];
#pragma unroll
  for (int a = 0; a < 2; ++a)
#pragma unroll
    for (int b = 0; b < 4; ++b) acc[a][b] = (float4v)0.f;

  uint4 TA[4], TB[4];

  // taps for chunk c: kk = c>>2, cg = c&3
  auto issueT = [&](uint4 (&T)[4], int c) {
    int4 g = s_gi[c >> 2][p];
    int cb = ((c & 3) << 6) + (coct << 3);
    T[0] = *reinterpret_cast<const uint4*>(xTn + g.x + cb);
    T[1] = *reinterpret_cast<const uint4*>(xTn + g.y + cb);
    T[2] = *reinterpret_cast<const uint4*>(xTn + g.z + cb);
    T[3] = *reinterpret_cast<const uint4*>(xTn + g.w + cb);
  };

  // pack chunk c (from taps T) into s_val[buf]
  auto pack = [&](uint4 (&T)[4], int c, int buf) {
    float4 w = s_gw[c >> 2][p];
    uint4 r;
    r.x = bilin_pack(T[0].x, T[1].x, T[2].x, T[3].x, w.x, w.y, w.z, w.w);
    r.y = bilin_pack(T[0].y, T[1].y, T[2].y, T[3].y, w.x, w.y, w.z, w.w);
    r.z = bilin_pack(T[0].z, T[1].z, T[2].z, T[3].z, w.x, w.y, w.z, w.w);
    r.w = bilin_pack(T[0].w, T[1].w, T[2].w, T[3].w, w.x, w.y, w.z, w.w);
    *reinterpret_cast<uint4*>(&s_val[buf][p * 64 + ((coct ^ (p & 7)) << 3)]) = r;
  };

  // MFMA for chunk m from s_val[buf]; wf pre-loaded by caller
  auto mfma_exec = [&](short8v (&wf)[2][2], int buf) {
    __builtin_amdgcn_s_setprio(1);
#pragma unroll
    for (int ks2 = 0; ks2 < 2; ++ks2) {
#pragma unroll
      for (int pf = 0; pf < 4; ++pf) {
        int row = (pf << 4) + (lane & 15);
        int g = (ks2 << 2) + (lane >> 4);
        int slot = g ^ (row & 7);
        short8v vf = *reinterpret_cast<const short8v*>(&s_val[buf][row * 64 + slot * 8]);
#pragma unroll
        for (int mf = 0; mf < 2; ++mf)
          acc[mf][pf] = __builtin_amdgcn_mfma_f32_16x16x32_bf16(
              wf[ks2][mf], vf, acc[mf][pf], 0, 0, 0);
      }
    }
    __builtin_amdgcn_s_setprio(0);
  };

  auto load_wf = [&](short8v (&wf)[2][2], int m) {
    int ks0 = m << 1;
#pragma unroll
    for (int ks2 = 0; ks2 < 2; ++ks2)
#pragma unroll
      for (int mf = 0; mf < 2; ++mf)
        wf[ks2][mf] = *reinterpret_cast<const short8v*>(
            &wB[(((size_t)((ks0 + ks2) * 16 + (wave << 1) + mf)) * 64 + lane) * 8]);
  };

  // ---- prologue: pack chunk 0, no MFMA yet ----
  issueT(TA, 0);
  issueT(TB, 1);
  pack(TA, 0, 0);
  asm volatile("s_waitcnt lgkmcnt(0)" ::: "memory");
  __builtin_amdgcn_s_barrier();

  // ---- skewed main loop: iterate chunk pairs (odd cc packs from TB) ----
  for (int cc = 1; cc < 36; cc += 2) {
    {
      // pack chunk cc (taps in TB), MFMA chunk cc-1 (buf[(cc-1)&1] = buf0)
      if (cc < 35) issueT(TA, cc + 1);
      short8v wf[2][2];
      load_wf(wf, cc - 1);
      pack(TB, cc, 1);
      mfma_exec(wf, 0);
      asm volatile("s_waitcnt lgkmcnt(0)" ::: "memory");
      __builtin_amdgcn_s_barrier();
    }
    if (cc + 1 < 36) {
      // pack chunk cc+1 (taps in TA), MFMA chunk cc (buf1)
      if (cc + 2 < 36) issueT(TB, cc + 2);
      short8v wf[2][2];
      load_wf(wf, cc);
      pack(TA, cc + 1, 0);
      mfma_exec(wf, 1);
      asm volatile("s_waitcnt lgkmcnt(0)" ::: "memory");
      __builtin_amdgcn_s_barrier();
    }
  }

  // ---- epilogue: MFMA last chunk (35, buf1) ----
  {
    short8v wf[2][2];
    load_wf(wf, 35);
    mfma_exec(wf, 1);
  }

  // ---- epilogue: out NCHW + per-block BN partials ----
#pragma unroll
  for (int mf = 0; mf < 2; ++mf) {
    int ocb = (wave << 5) + (mf << 4) + ((lane >> 4) << 2);
#pragma unroll
    for (int pf = 0; pf < 4; ++pf) {
      int wo = (pf << 4) + (lane & 15);
      float* op = out + (((size_t)(n * 256 + ocb)) * 64 + ho) * 64 + wo;
      float4v a = acc[mf][pf];
      op[0] = a[0];
      op[HW] = a[1];
      op[2 * HW] = a[2];
      op[3 * HW] = a[3];
    }
  }
  float s[2][4], q[2][4];
#pragma unroll
  for (int mf = 0; mf < 2; ++mf)
#pragma unroll
    for (int j = 0; j < 4; ++j) {
      float ss = 0.f, qq = 0.f;
#pragma unroll
      for (int pf = 0; pf < 4; ++pf) {
        float v = acc[mf][pf][j];
        ss += v;
        qq += v * v;
      }
      s[mf][j] = ss;
      q[mf][j] = qq;
    }
#pragma unroll
  for (int o = 1; o < 16; o <<= 1) {
#pragma unroll
    for (int mf = 0; mf < 2; ++mf)
#pragma unroll
      for (int j = 0; j < 4; ++j) {
        s[mf][j] += __shfl_xor(s[mf][j], o);
        q[mf][j] += __shfl_xor(q[mf][j], o);
      }
  }
  if ((lane & 15) == 0) {
#pragma unroll
    for (int mf = 0; mf < 2; ++mf)
#pragma unroll
      for (int j = 0; j < 4; ++j) {
        int oc = (wave << 5) + (mf << 4) + ((lane >> 4) << 2) + j;
        part[(size_t)oc * 512 + bid] = make_float2(s[mf][j], q[mf][j]);
      }
  }
}

__global__ __launch_bounds__(256) void k_stats_fin(const float2* __restrict__ part,
                                                   float2* __restrict__ stats) {
  int oc = blockIdx.x;
  int t = threadIdx.x;
  float2 a = part[(size_t)oc * 512 + t];
  float2 b = part[(size_t)oc * 512 + 256 + t];
  float s = a.x + b.x, q = a.y + b.y;
#pragma unroll
  for (int o = 32; o; o >>= 1) {
    s += __shfl_down(s, o);
    q += __shfl_down(q, o);
  }
  __shared__ float2 wsum[4];
  if ((t & 63) == 0) wsum[t >> 6] = make_float2(s, q);
  __syncthreads();
  if (t == 0) {
    float S = wsum[0].x + wsum[1].x + wsum[2].x + wsum[3].x;
    float Q = wsum[0].y + wsum[1].y + wsum[2].y + wsum[3].y;
    float mean = S / 32768.f;
    float var = Q / 32768.f - mean * mean;
    stats[oc] = make_float2(mean, rsqrtf(var + 1e-5f));
  }
}

// BN+SiLU, XCD-aligned: blocks for image n land on XCD n.
__global__ __launch_bounds__(256) void k_bn_silu(float* __restrict__ out,
                                                 const float2* __restrict__ stats,
                                                 const float* __restrict__ gamma,
                                                 const float* __restrict__ beta) {
  int b = blockIdx.x;
  int nb = (b & 7) * 1024 + (b >> 3);   // image = b&7
  size_t i4 = (size_t)nb * 256 + threadIdx.x;
  int ch = (int)((i4 >> 10) & 255);
  float2 st = stats[ch];
  float g = gamma[ch] * st.y;
  float bb = beta[ch] - st.x * g;
  float4 v = *(float4*)(out + i4 * 4);
  float y0 = v.x * g + bb, y1 = v.y * g + bb, y2 = v.z * g + bb, y3 = v.w * g + bb;
  v.x = y0 / (1.f + expf(-y0));
  v.y = y1 / (1.f + expf(-y1));
  v.z = y2 / (1.f + expf(-y2));
  v.w = y3 / (1.f + expf(-y3));
  *(float4*)(out + i4 * 4) = v;
}

extern "C" void kernel_launch(void* const* d_in, const int* in_sizes, int n_in,
                              void* d_out, int out_size, void* d_ws, size_t ws_size,
                              hipStream_t stream) {
  const float* x      = (const float*)d_in[0];
  const float* w_off  = (const float*)d_in[1];
  const float* b_off  = (const float*)d_in[2];
  const float* w_conv = (const float*)d_in[3];
  const float* gamma  = (const float*)d_in[4];
  const float* beta   = (const float*)d_in[5];
  float* out = (float*)d_out;

  float* ws       = (float*)d_ws;
  float*  ws_off  = ws;                               // [8][4096][18] f32
  ushort* ws_xT   = (ushort*)(ws + 589824);           // [8][4096][256] bf16
  ushort* ws_wB   = (ushort*)(ws + 4784128);          // deform weight frags
  ushort* ws_wOB  = (ushort*)(ws + 5079040);          // offset weight frags
  float2* ws_part = (float2*)(ws + 5115904);          // [256][512] partials
  float2* ws_st   = (float2*)(ws + 5378048);          // [256] stats

  k_tx_prep<<<836, 256, 0, stream>>>(x, w_conv, w_off, ws_xT, ws_wB, ws_wOB);
  k_offset5<<<512, 512, 0, stream>>>(ws_xT, ws_wOB, b_off, ws_off);
  k_deform11<<<512, 512, 0, stream>>>(ws_xT, ws_off, ws_wB, out, ws_part);
  k_stats_fin<<<256, 256, 0, stream>>>(ws_part, ws_st);
  k_bn_silu<<<8192, 256, 0, stream>>>(out, ws_st, gamma, beta);
}

// Round 15
// 108.563 us; speedup vs baseline: 1.0239x; 1.0239x over previous
//
#include <hip/hip_runtime.h>
#include <math.h>

#define HW 4096
#define KTOT 2304   // 256 * 9

typedef __attribute__((ext_vector_type(8))) short short8v;
typedef __attribute__((ext_vector_type(4))) float float4v;

__device__ __forceinline__ unsigned int bf16rne(float f) {
  unsigned int x = __float_as_uint(f);
  return (x + 0x7fffu + ((x >> 16) & 1u)) >> 16;
}

__device__ __forceinline__ unsigned int bilin_pack(unsigned int u0, unsigned int u1,
                                                   unsigned int u2, unsigned int u3,
                                                   float w0, float w1, float w2, float w3) {
  float lo = w0 * __uint_as_float(u0 << 16) + w1 * __uint_as_float(u1 << 16) +
             w2 * __uint_as_float(u2 << 16) + w3 * __uint_as_float(u3 << 16);
  float hi = w0 * __uint_as_float(u0 & 0xFFFF0000u) + w1 * __uint_as_float(u1 & 0xFFFF0000u) +
             w2 * __uint_as_float(u2 & 0xFFFF0000u) + w3 * __uint_as_float(u3 & 0xFFFF0000u);
  unsigned int r;
  asm("v_cvt_pk_bf16_f32 %0, %1, %2" : "=v"(r) : "v"(lo), "v"(hi));
  return r;
}

// ------------------------------------------------------------------
// ws layout (float offsets):
//   0        : off      [8][4096][18] f32
//   589824   : xT       [8][4096][256] bf16
//   4784128  : wB       [72][16][64][8] bf16
//   5079040  : wOffB    [72][2][64][8] bf16
//   5115904  : part     [256 oc][512] float2
//   5378048  : stats    [256] float2
// ------------------------------------------------------------------

// Merged: blocks [0,512) transpose x -> NHWC bf16 (n = bid&7, XCD-aligned);
// [512,800) pack w_conv frags; [800,836) pack w_offset frags.
__global__ __launch_bounds__(256) void k_tx_prep(const float* __restrict__ x,
                                                 const float* __restrict__ wc,
                                                 const float* __restrict__ wo,
                                                 ushort* __restrict__ xT,
                                                 ushort* __restrict__ wB,
                                                 ushort* __restrict__ wOB) {
  int bid = blockIdx.x;
  if (bid < 512) {
    int n = bid & 7, p0 = (bid >> 3) << 6;
    int t = threadIdx.x;
    int lane = t & 63, wave = t >> 6, c0 = wave << 6;
    const float* xb = x + ((size_t)(n * 256 + c0)) * HW + p0 + lane;
    ushort* ob = xT + ((size_t)n * 4096 + p0 + lane) * 256 + c0;
#pragma unroll
    for (int g = 0; g < 8; ++g) {
      unsigned int u[4];
#pragma unroll
      for (int j = 0; j < 4; ++j) {
        float v0 = xb[(size_t)(g * 8 + 2 * j) * HW];
        float v1 = xb[(size_t)(g * 8 + 2 * j + 1) * HW];
        u[j] = bf16rne(v0) | (bf16rne(v1) << 16);
      }
      *reinterpret_cast<uint4*>(ob + g * 8) = make_uint4(u[0], u[1], u[2], u[3]);
    }
  } else if (bid < 800) {
    int t = (bid - 512) * 256 + threadIdx.x;   // 73728
    int ks = t >> 10;
    int l = t & 63;
    int of = (t >> 6) & 15;
    int kk = ks >> 3;
    int cbase = ((ks & 7) << 5) + ((l >> 4) << 3);
    int oc = (of << 4) + (l & 15);
    unsigned int u[8];
#pragma unroll
    for (int j = 0; j < 8; ++j)
      u[j] = bf16rne(wc[(size_t)oc * KTOT + (size_t)(cbase + j) * 9 + kk]);
    *reinterpret_cast<uint4*>(&wB[(size_t)t * 8]) =
        make_uint4(u[0] | (u[1] << 16), u[2] | (u[3] << 16),
                   u[4] | (u[5] << 16), u[6] | (u[7] << 16));
  } else {
    int t = (bid - 800) * 256 + threadIdx.x;   // 9216
    int ks = t >> 7;
    int l = t & 63;
    int of = (t >> 6) & 1;
    int kk = ks >> 3;
    int cbase = ((ks & 7) << 5) + ((l >> 4) << 3);
    int oc = (of << 4) + (l & 15);
    unsigned int u[8];
#pragma unroll
    for (int j = 0; j < 8; ++j)
      u[j] = (oc < 18) ? bf16rne(wo[(size_t)oc * KTOT + (size_t)(cbase + j) * 9 + kk]) : 0u;
    *reinterpret_cast<uint4*>(&wOB[(size_t)t * 8]) =
        make_uint4(u[0] | (u[1] << 16), u[2] | (u[3] << 16),
                   u[4] | (u[5] << 16), u[6] | (u[7] << 16));
  }
}

// ------------------------------------------------------------------
// Offset conv implicit GEMM — R13-proven k_offset5, unchanged.
// ------------------------------------------------------------------
__global__ __launch_bounds__(512, 4) void k_offset5(
    const ushort* __restrict__ xT, const ushort* __restrict__ wOffB,
    const float* __restrict__ b_off, float* __restrict__ off_out) {
  __shared__ ushort s_tile[2][64 * 64];   // 16 KB

  int bid = blockIdx.x;
  int n = bid & 7, ho = bid >> 3;
  int t = threadIdx.x;
  int lane = t & 63, wave = t >> 6;
  int coct = lane & 7;
  int p = (wave << 3) + (lane >> 3);
  int ocf = wave & 1, pixf = wave >> 1;

  const ushort* xTn = xT + (size_t)n * 4096 * 256;

  float4v acc = (float4v)0.f;

  auto srcp = [&](int kk, const ushort*& s, bool& v) {
    int ky = kk / 3, kx = kk - ky * 3;
    int oy = ho + ky - 1, ox = p + kx - 1;
    v = (oy >= 0) & (oy < 64) & (ox >= 0) & (ox < 64);
    s = xTn + (size_t)(oy * 64 + ox) * 256 + (coct << 3);
  };

  auto issue = [&](uint4& a, const ushort* s, bool v, int cg) {
    a = v ? *reinterpret_cast<const uint4*>(s + (cg << 6)) : make_uint4(0, 0, 0, 0);
  };

  auto step = [&](uint4 a, int ksb, int buf) {
    short8v wf[2];
#pragma unroll
    for (int ks2 = 0; ks2 < 2; ++ks2)
      wf[ks2] = *reinterpret_cast<const short8v*>(
          &wOffB[(((size_t)((ksb + ks2) * 2 + ocf)) * 64 + lane) * 8]);
    *reinterpret_cast<uint4*>(&s_tile[buf][p * 64 + ((coct ^ (p & 7)) << 3)]) = a;
    asm volatile("s_waitcnt lgkmcnt(0)" ::: "memory");
    __builtin_amdgcn_s_barrier();
#pragma unroll
    for (int ks2 = 0; ks2 < 2; ++ks2) {
      int row = (pixf << 4) + (lane & 15);
      int g = (ks2 << 2) + (lane >> 4);
      int slot = g ^ (row & 7);
      short8v vf = *reinterpret_cast<const short8v*>(&s_tile[buf][row * 64 + slot * 8]);
      acc = __builtin_amdgcn_mfma_f32_16x16x32_bf16(wf[ks2], vf, acc, 0, 0, 0);
    }
  };

  const ushort* cs;
  bool cv;
  srcp(0, cs, cv);
  uint4 A, B;
  issue(A, cs, cv, 0);

  for (int kk = 0; kk < 9; ++kk) {
    int ksb = kk << 3;
    issue(B, cs, cv, 1);
    step(A, ksb + 0, 0);
    issue(A, cs, cv, 2);
    step(B, ksb + 2, 1);
    issue(B, cs, cv, 3);
    step(A, ksb + 4, 0);
    const ushort* ns = cs;
    bool nv = cv;
    if (kk < 8) {
      srcp(kk + 1, ns, nv);
      issue(A, ns, nv, 0);
    }
    step(B, ksb + 6, 1);
    cs = ns; cv = nv;
  }

  int pixcol = (pixf << 4) + (lane & 15);
  size_t base = ((size_t)n * 4096 + ho * 64 + pixcol) * 18;
#pragma unroll
  for (int j = 0; j < 4; ++j) {
    int oc = (ocf << 4) + ((lane >> 4) << 2) + j;
    if (oc < 18) off_out[base + oc] = acc[j] + b_off[oc];
  }
}

// ------------------------------------------------------------------
// Deformable conv implicit GEMM — R13 skeleton with 2-chunk phases:
// 18 phases x {pack 2 chunks (same kk, 128 c) -> s_val[buf]; issue next
// phase's 8 tap loads; load wf ks01; drain; ONE barrier; issue wf ks23;
// MFMA 4 ksteps}. Halves barrier+drain count; geometry read once/phase.
// Block: 512 thr, 8 waves, 64 pix x 256 oc, grid 512, n=bid&7, 2 blk/CU.
// ------------------------------------------------------------------
__global__ __launch_bounds__(512, 4) void k_deform12(
    const ushort* __restrict__ xT, const float* __restrict__ off,
    const ushort* __restrict__ wB, float* __restrict__ out,
    float2* __restrict__ part) {
  __shared__ ushort s_val[2][64 * 128];  // 32 KB (dbuf of 16 KB phases)
  __shared__ int4   s_gi[9][64];         // 9.2 KB
  __shared__ float4 s_gw[9][64];         // 9.2 KB

  int bid = blockIdx.x;
  int n = bid & 7, ho = bid >> 3;
  int t = threadIdx.x;
  int lane = t & 63, wave = t >> 6;
  int coct = lane & 7;
  int p = (wave << 3) + (lane >> 3);   // 0..63, this thread's pixel

  const ushort* xTn = xT + (size_t)n * 4096 * 256;

  // ---- phase 0: bilinear geometry for all (kk, pix) ----
  for (int e = t; e < 576; e += 512) {
    int pix = e & 63, kk = e >> 6;
    int ky = kk / 3, kx = kk - ky * 3;
    const float* ob = off + ((size_t)n * 4096 + ho * 64 + pix) * 18;
    float dy = ob[2 * kk], dx = ob[2 * kk + 1];
    float py = (float)(ho - 1 + ky) + dy;
    float px = (float)(pix - 1 + kx) + dx;
    float y0f = floorf(py), x0f = floorf(px);
    float ly = py - y0f, lx = px - x0f;
    int y0 = (int)y0f, x0 = (int)x0f;
    int y1 = y0 + 1, x1 = x0 + 1;
    float vy0 = (y0 >= 0 && y0 < 64) ? 1.f : 0.f;
    float vy1 = (y1 >= 0 && y1 < 64) ? 1.f : 0.f;
    float vx0 = (x0 >= 0 && x0 < 64) ? 1.f : 0.f;
    float vx1 = (x1 >= 0 && x1 < 64) ? 1.f : 0.f;
    int cy0 = min(max(y0, 0), 63) << 6, cy1 = min(max(y1, 0), 63) << 6;
    int cx0 = min(max(x0, 0), 63), cx1 = min(max(x1, 0), 63);
    s_gi[kk][pix] = make_int4((cy0 + cx0) << 8, (cy0 + cx1) << 8,
                              (cy1 + cx0) << 8, (cy1 + cx1) << 8);
    s_gw[kk][pix] = make_float4((1.f - ly) * (1.f - lx) * vy0 * vx0,
                                (1.f - ly) * lx * vy0 * vx1,
                                ly * (1.f - lx) * vy1 * vx0,
                                ly * lx * vy1 * vx1);
  }
  __syncthreads();

  float4v acc[2][4];
#pragma unroll
  for (int a = 0; a < 2; ++a)
#pragma unroll
    for (int b = 0; b < 4; ++b) acc[a][b] = (float4v)0.f;

  uint4 TA[4], TB[4];

  // issue taps for chunk c (cg = c&3) from preloaded geometry g
  auto issueT = [&](uint4 (&T)[4], const int4& g, int c) {
    int cb = ((c & 3) << 6) + (coct << 3);
    T[0] = *reinterpret_cast<const uint4*>(xTn + g.x + cb);
    T[1] = *reinterpret_cast<const uint4*>(xTn + g.y + cb);
    T[2] = *reinterpret_cast<const uint4*>(xTn + g.z + cb);
    T[3] = *reinterpret_cast<const uint4*>(xTn + g.w + cb);
  };

  // pack chunk c (taps T, weights w) into s_val[buf], c-half = c&1
  auto pack = [&](uint4 (&T)[4], const float4& w, int c, int buf) {
    uint4 r;
    r.x = bilin_pack(T[0].x, T[1].x, T[2].x, T[3].x, w.x, w.y, w.z, w.w);
    r.y = bilin_pack(T[0].y, T[1].y, T[2].y, T[3].y, w.x, w.y, w.z, w.w);
    r.z = bilin_pack(T[0].z, T[1].z, T[2].z, T[3].z, w.x, w.y, w.z, w.w);
    r.w = bilin_pack(T[0].w, T[1].w, T[2].w, T[3].w, w.x, w.y, w.z, w.w);
    *reinterpret_cast<uint4*>(
        &s_val[buf][p * 128 + ((c & 1) << 6) + ((coct ^ (p & 7)) << 3)]) = r;
  };

  auto load_wf2 = [&](short8v (&wf)[2][2], int ksbase) {
#pragma unroll
    for (int ks2 = 0; ks2 < 2; ++ks2)
#pragma unroll
      for (int mf = 0; mf < 2; ++mf)
        wf[ks2][mf] = *reinterpret_cast<const short8v*>(
            &wB[(((size_t)((ksbase + ks2) * 16 + (wave << 1) + mf)) * 64 + lane) * 8]);
  };

  // MFMA 2 ksteps from s_val[buf] half `half` (0 or 1)
  auto mfma2 = [&](short8v (&wf)[2][2], int buf, int half) {
#pragma unroll
    for (int ks2 = 0; ks2 < 2; ++ks2) {
#pragma unroll
      for (int pf = 0; pf < 4; ++pf) {
        int row = (pf << 4) + (lane & 15);
        int g = (ks2 << 2) + (lane >> 4);
        int slot = g ^ (row & 7);
        short8v vf = *reinterpret_cast<const short8v*>(
            &s_val[buf][row * 128 + (half << 6) + slot * 8]);
#pragma unroll
        for (int mf = 0; mf < 2; ++mf)
          acc[mf][pf] = __builtin_amdgcn_mfma_f32_16x16x32_bf16(
              wf[ks2][mf], vf, acc[mf][pf], 0, 0, 0);
      }
    }
  };

  {
    int4 g0 = s_gi[0][p];
    issueT(TA, g0, 0);
    issueT(TB, g0, 1);
  }

  for (int ph = 0; ph < 18; ++ph) {
    int kk = ph >> 1;
    int buf = ph & 1;
    float4 w = s_gw[kk][p];
    pack(TA, w, 2 * ph, buf);
    pack(TB, w, 2 * ph + 1, buf);
    if (ph < 17) {
      int4 g = s_gi[(ph + 1) >> 1][p];
      issueT(TA, g, 2 * ph + 2);
      issueT(TB, g, 2 * ph + 3);
    }
    short8v wf01[2][2];
    load_wf2(wf01, 4 * ph);
    asm volatile("s_waitcnt lgkmcnt(0)" ::: "memory");
    __builtin_amdgcn_s_barrier();
    short8v wf23[2][2];
    load_wf2(wf23, 4 * ph + 2);
    __builtin_amdgcn_s_setprio(1);
    mfma2(wf01, buf, 0);
    mfma2(wf23, buf, 1);
    __builtin_amdgcn_s_setprio(0);
  }

  // ---- epilogue: out NCHW + per-block BN partials ----
#pragma unroll
  for (int mf = 0; mf < 2; ++mf) {
    int ocb = (wave << 5) + (mf << 4) + ((lane >> 4) << 2);
#pragma unroll
    for (int pf = 0; pf < 4; ++pf) {
      int wo = (pf << 4) + (lane & 15);
      float* op = out + (((size_t)(n * 256 + ocb)) * 64 + ho) * 64 + wo;
      float4v a = acc[mf][pf];
      op[0] = a[0];
      op[HW] = a[1];
      op[2 * HW] = a[2];
      op[3 * HW] = a[3];
    }
  }
  float s[2][4], q[2][4];
#pragma unroll
  for (int mf = 0; mf < 2; ++mf)
#pragma unroll
    for (int j = 0; j < 4; ++j) {
      float ss = 0.f, qq = 0.f;
#pragma unroll
      for (int pf = 0; pf < 4; ++pf) {
        float v = acc[mf][pf][j];
        ss += v;
        qq += v * v;
      }
      s[mf][j] = ss;
      q[mf][j] = qq;
    }
#pragma unroll
  for (int o = 1; o < 16; o <<= 1) {
#pragma unroll
    for (int mf = 0; mf < 2; ++mf)
#pragma unroll
      for (int j = 0; j < 4; ++j) {
        s[mf][j] += __shfl_xor(s[mf][j], o);
        q[mf][j] += __shfl_xor(q[mf][j], o);
      }
  }
  if ((lane & 15) == 0) {
#pragma unroll
    for (int mf = 0; mf < 2; ++mf)
#pragma unroll
      for (int j = 0; j < 4; ++j) {
        int oc = (wave << 5) + (mf << 4) + ((lane >> 4) << 2) + j;
        part[(size_t)oc * 512 + bid] = make_float2(s[mf][j], q[mf][j]);
      }
  }
}

__global__ __launch_bounds__(256) void k_stats_fin(const float2* __restrict__ part,
                                                   float2* __restrict__ stats) {
  int oc = blockIdx.x;
  int t = threadIdx.x;
  float2 a = part[(size_t)oc * 512 + t];
  float2 b = part[(size_t)oc * 512 + 256 + t];
  float s = a.x + b.x, q = a.y + b.y;
#pragma unroll
  for (int o = 32; o; o >>= 1) {
    s += __shfl_down(s, o);
    q += __shfl_down(q, o);
  }
  __shared__ float2 wsum[4];
  if ((t & 63) == 0) wsum[t >> 6] = make_float2(s, q);
  __syncthreads();
  if (t == 0) {
    float S = wsum[0].x + wsum[1].x + wsum[2].x + wsum[3].x;
    float Q = wsum[0].y + wsum[1].y + wsum[2].y + wsum[3].y;
    float mean = S / 32768.f;
    float var = Q / 32768.f - mean * mean;
    stats[oc] = make_float2(mean, rsqrtf(var + 1e-5f));
  }
}

// BN+SiLU, XCD-aligned: blocks for image n land on XCD n.
__global__ __launch_bounds__(256) void k_bn_silu(float* __restrict__ out,
                                                 const float2* __restrict__ stats,
                                                 const float* __restrict__ gamma,
                                                 const float* __restrict__ beta) {
  int b = blockIdx.x;
  int nb = (b & 7) * 1024 + (b >> 3);   // image = b&7
  size_t i4 = (size_t)nb * 256 + threadIdx.x;
  int ch = (int)((i4 >> 10) & 255);
  float2 st = stats[ch];
  float g = gamma[ch] * st.y;
  float bb = beta[ch] - st.x * g;
  float4 v = *(float4*)(out + i4 * 4);
  float y0 = v.x * g + bb, y1 = v.y * g + bb, y2 = v.z * g + bb, y3 = v.w * g + bb;
  v.x = y0 / (1.f + expf(-y0));
  v.y = y1 / (1.f + expf(-y1));
  v.z = y2 / (1.f + expf(-y2));
  v.w = y3 / (1.f + expf(-y3));
  *(float4*)(out + i4 * 4) = v;
}

extern "C" void kernel_launch(void* const* d_in, const int* in_sizes, int n_in,
                              void* d_out, int out_size, void* d_ws, size_t ws_size,
                              hipStream_t stream) {
  const float* x      = (const float*)d_in[0];
  const float* w_off  = (const float*)d_in[1];
  const float* b_off  = (const float*)d_in[2];
  const float* w_conv = (const float*)d_in[3];
  const float* gamma  = (const float*)d_in[4];
  const float* beta   = (const float*)d_in[5];
  float* out = (float*)d_out;

  float* ws       = (float*)d_ws;
  float*  ws_off  = ws;                               // [8][4096][18] f32
  ushort* ws_xT   = (ushort*)(ws + 589824);           // [8][4096][256] bf16
  ushort* ws_wB   = (ushort*)(ws + 4784128);          // deform weight frags
  ushort* ws_wOB  = (ushort*)(ws + 5079040);          // offset weight frags
  float2* ws_part = (float2*)(ws + 5115904);          // [256][512] partials
  float2* ws_st   = (float2*)(ws + 5378048);          // [256] stats

  k_tx_prep<<<836, 256, 0, stream>>>(x, w_conv, w_off, ws_xT, ws_wB, ws_wOB);
  k_offset5<<<512, 512, 0, stream>>>(ws_xT, ws_wOB, b_off, ws_off);
  k_deform12<<<512, 512, 0, stream>>>(ws_xT, ws_off, ws_wB, out, ws_part);
  k_stats_fin<<<256, 256, 0, stream>>>(ws_part, ws_st);
  k_bn_silu<<<8192, 256, 0, stream>>>(out, ws_st, gamma, beta);
}

// Round 16
// 102.682 us; speedup vs baseline: 1.0825x; 1.0573x over previous
//
#include <hip/hip_runtime.h>
#include <math.h>

#define HW 4096
#define KTOT 2304   // 256 * 9

typedef __attribute__((ext_vector_type(8))) short short8v;
typedef __attribute__((ext_vector_type(4))) float float4v;

__device__ __forceinline__ unsigned int bf16rne(float f) {
  unsigned int x = __float_as_uint(f);
  return (x + 0x7fffu + ((x >> 16) & 1u)) >> 16;
}

__device__ __forceinline__ unsigned int cvtpk(float lo, float hi) {
  unsigned int r;
  asm("v_cvt_pk_bf16_f32 %0, %1, %2" : "=v"(r) : "v"(lo), "v"(hi));
  return r;
}

__device__ __forceinline__ unsigned int bilin_pack(unsigned int u0, unsigned int u1,
                                                   unsigned int u2, unsigned int u3,
                                                   float w0, float w1, float w2, float w3) {
  float lo = w0 * __uint_as_float(u0 << 16) + w1 * __uint_as_float(u1 << 16) +
             w2 * __uint_as_float(u2 << 16) + w3 * __uint_as_float(u3 << 16);
  float hi = w0 * __uint_as_float(u0 & 0xFFFF0000u) + w1 * __uint_as_float(u1 & 0xFFFF0000u) +
             w2 * __uint_as_float(u2 & 0xFFFF0000u) + w3 * __uint_as_float(u3 & 0xFFFF0000u);
  return cvtpk(lo, hi);
}

// ------------------------------------------------------------------
// ws layout (float offsets):
//   589824   : xT       [8][4096][256] bf16
//   4784128  : wB       [72][16][64][8] bf16
//   5079040  : wOffB    [72][2][64][8] bf16
//   5115904  : part     [256 oc][512] float2
//   5378048  : stats    [256] float2
// ------------------------------------------------------------------

// Merged: blocks [0,512) transpose x -> NHWC bf16 via LDS (coalesced both
// sides; n = bid&7 XCD-aligned); [512,800) pack w_conv; [800,836) w_offset.
__global__ __launch_bounds__(256) void k_tx_prep(const float* __restrict__ x,
                                                 const float* __restrict__ wc,
                                                 const float* __restrict__ wo,
                                                 ushort* __restrict__ xT,
                                                 ushort* __restrict__ wB,
                                                 ushort* __restrict__ wOB) {
  __shared__ unsigned s32[64 * 129];   // 33 KB, pad-129 -> conflict-free
  int bid = blockIdx.x;
  if (bid < 512) {
    int n = bid & 7, p0 = (bid >> 3) << 6;
    int t = threadIdx.x;
    int pixr = t & 63;          // read-phase pixel (lane-contiguous)
    int cq = t >> 6;            // 0..3
    const float* xb = x + ((size_t)n * 256) * HW + p0 + pixr;
#pragma unroll 4
    for (int g = 0; g < 32; ++g) {
      int c0 = (g << 3) + (cq << 1);
      float v0 = xb[(size_t)c0 * HW];
      float v1 = xb[(size_t)(c0 + 1) * HW];
      s32[pixr * 129 + (c0 >> 1)] = cvtpk(v0, v1);
    }
    __syncthreads();
    int cslot = t & 31;          // 16B slot within a pixel row
    int pw = t >> 5;             // 0..7
#pragma unroll
    for (int pass = 0; pass < 8; ++pass) {
      int pix = (pass << 3) + pw;
      uint4 v = *reinterpret_cast<const uint4*>(&s32[pix * 129 + (cslot << 2)]);
      *reinterpret_cast<uint4*>(
          &xT[((size_t)(n * 4096 + p0 + pix)) * 256 + (cslot << 3)]) = v;
    }
  } else if (bid < 800) {
    int t = (bid - 512) * 256 + threadIdx.x;   // 73728
    int ks = t >> 10;
    int l = t & 63;
    int of = (t >> 6) & 15;
    int kk = ks >> 3;
    int cbase = ((ks & 7) << 5) + ((l >> 4) << 3);
    int oc = (of << 4) + (l & 15);
    unsigned int u[8];
#pragma unroll
    for (int j = 0; j < 8; ++j)
      u[j] = bf16rne(wc[(size_t)oc * KTOT + (size_t)(cbase + j) * 9 + kk]);
    *reinterpret_cast<uint4*>(&wB[(size_t)t * 8]) =
        make_uint4(u[0] | (u[1] << 16), u[2] | (u[3] << 16),
                   u[4] | (u[5] << 16), u[6] | (u[7] << 16));
  } else {
    int t = (bid - 800) * 256 + threadIdx.x;   // 9216
    int ks = t >> 7;
    int l = t & 63;
    int of = (t >> 6) & 1;
    int kk = ks >> 3;
    int cbase = ((ks & 7) << 5) + ((l >> 4) << 3);
    int oc = (of << 4) + (l & 15);
    unsigned int u[8];
#pragma unroll
    for (int j = 0; j < 8; ++j)
      u[j] = (oc < 18) ? bf16rne(wo[(size_t)oc * KTOT + (size_t)(cbase + j) * 9 + kk]) : 0u;
    *reinterpret_cast<uint4*>(&wOB[(size_t)t * 8]) =
        make_uint4(u[0] | (u[1] << 16), u[2] | (u[3] << 16),
                   u[4] | (u[5] << 16), u[6] | (u[7] << 16));
  }
}

// ------------------------------------------------------------------
// FUSED offset conv + deformable conv. Block: 512 thr, (n = bid&7, ho).
// Phase 1: offset conv for this block's 64 pixels (k_offset5 inner loop,
//          staging in s_val) -> s_off[64][20] in LDS.
// Phase 2: bilinear geometry from s_off.
// Phase 3: main implicit-GEMM loop = R13's proven k_deform10 verbatim.
// ------------------------------------------------------------------
__global__ __launch_bounds__(512, 4) void k_dfull(
    const ushort* __restrict__ xT, const ushort* __restrict__ wB,
    const ushort* __restrict__ wOB, const float* __restrict__ b_off,
    float* __restrict__ out, float2* __restrict__ part) {
  __shared__ ushort s_val[2][64 * 64];   // 16 KB (shared by both phases)
  __shared__ int4   s_gi[9][64];         // 9.2 KB
  __shared__ float4 s_gw[9][64];         // 9.2 KB
  __shared__ float  s_off[64][20];       // 5 KB

  int bid = blockIdx.x;
  int n = bid & 7, ho = bid >> 3;
  int t = threadIdx.x;
  int lane = t & 63, wave = t >> 6;
  int coct = lane & 7;
  int p = (wave << 3) + (lane >> 3);   // 0..63, this thread's pixel

  const ushort* xTn = xT + (size_t)n * 4096 * 256;

  // ======== phase 1: offset conv (64 pix x 18 oc) ========
  {
    int ocf = wave & 1, pixf = wave >> 1;
    float4v aoff = (float4v)0.f;

    auto srcp = [&](int kk, const ushort*& s, bool& v) {
      int ky = kk / 3, kx = kk - ky * 3;
      int oy = ho + ky - 1, ox = p + kx - 1;
      v = (oy >= 0) & (oy < 64) & (ox >= 0) & (ox < 64);
      s = xTn + (size_t)(oy * 64 + ox) * 256 + (coct << 3);
    };
    auto ld = [&](uint4& a, const ushort* s, bool v, int cg) {
      a = v ? *reinterpret_cast<const uint4*>(s + (cg << 6)) : make_uint4(0, 0, 0, 0);
    };
    auto ostep = [&](uint4 a, int ksb, int buf) {
      short8v wf[2];
#pragma unroll
      for (int ks2 = 0; ks2 < 2; ++ks2)
        wf[ks2] = *reinterpret_cast<const short8v*>(
            &wOB[(((size_t)((ksb + ks2) * 2 + ocf)) * 64 + lane) * 8]);
      *reinterpret_cast<uint4*>(&s_val[buf][p * 64 + ((coct ^ (p & 7)) << 3)]) = a;
      asm volatile("s_waitcnt lgkmcnt(0)" ::: "memory");
      __builtin_amdgcn_s_barrier();
#pragma unroll
      for (int ks2 = 0; ks2 < 2; ++ks2) {
        int row = (pixf << 4) + (lane & 15);
        int g = (ks2 << 2) + (lane >> 4);
        int slot = g ^ (row & 7);
        short8v vf = *reinterpret_cast<const short8v*>(&s_val[buf][row * 64 + slot * 8]);
        aoff = __builtin_amdgcn_mfma_f32_16x16x32_bf16(wf[ks2], vf, aoff, 0, 0, 0);
      }
    };

    const ushort* cs;
    bool cv;
    srcp(0, cs, cv);
    uint4 A, B;
    ld(A, cs, cv, 0);
    for (int kk = 0; kk < 9; ++kk) {
      int ksb = kk << 3;
      ld(B, cs, cv, 1);
      ostep(A, ksb + 0, 0);
      ld(A, cs, cv, 2);
      ostep(B, ksb + 2, 1);
      ld(B, cs, cv, 3);
      ostep(A, ksb + 4, 0);
      const ushort* ns = cs;
      bool nv = cv;
      if (kk < 8) {
        srcp(kk + 1, ns, nv);
        ld(A, ns, nv, 0);
      }
      ostep(B, ksb + 6, 1);
      cs = ns;
      cv = nv;
    }
    int pixcol = (pixf << 4) + (lane & 15);
#pragma unroll
    for (int j = 0; j < 4; ++j) {
      int oc = (ocf << 4) + ((lane >> 4) << 2) + j;
      if (oc < 18) s_off[pixcol][oc] = aoff[j] + b_off[oc];
    }
  }
  __syncthreads();

  // ======== phase 2: bilinear geometry for all (kk, pix) from s_off ====
  for (int e = t; e < 576; e += 512) {
    int pix = e & 63, kk = e >> 6;
    int ky = kk / 3, kx = kk - ky * 3;
    float dy = s_off[pix][2 * kk], dx = s_off[pix][2 * kk + 1];
    float py = (float)(ho - 1 + ky) + dy;
    float px = (float)(pix - 1 + kx) + dx;
    float y0f = floorf(py), x0f = floorf(px);
    float ly = py - y0f, lx = px - x0f;
    int y0 = (int)y0f, x0 = (int)x0f;
    int y1 = y0 + 1, x1 = x0 + 1;
    float vy0 = (y0 >= 0 && y0 < 64) ? 1.f : 0.f;
    float vy1 = (y1 >= 0 && y1 < 64) ? 1.f : 0.f;
    float vx0 = (x0 >= 0 && x0 < 64) ? 1.f : 0.f;
    float vx1 = (x1 >= 0 && x1 < 64) ? 1.f : 0.f;
    int cy0 = min(max(y0, 0), 63) << 6, cy1 = min(max(y1, 0), 63) << 6;
    int cx0 = min(max(x0, 0), 63), cx1 = min(max(x1, 0), 63);
    s_gi[kk][pix] = make_int4((cy0 + cx0) << 8, (cy0 + cx1) << 8,
                              (cy1 + cx0) << 8, (cy1 + cx1) << 8);
    s_gw[kk][pix] = make_float4((1.f - ly) * (1.f - lx) * vy0 * vx0,
                                (1.f - ly) * lx * vy0 * vx1,
                                ly * (1.f - lx) * vy1 * vx0,
                                ly * lx * vy1 * vx1);
  }
  __syncthreads();

  // ======== phase 3: main loop (R13 deform10 verbatim) ========
  float4v acc[2][4];
#pragma unroll
  for (int a = 0; a < 2; ++a)
#pragma unroll
    for (int b = 0; b < 4; ++b) acc[a][b] = (float4v)0.f;

  uint4 TA[4], TB[4];

  auto issue = [&](uint4 (&T)[4], int kk, int cg) {
    int4 g = s_gi[kk][p];
    int cb = (cg << 6) + (coct << 3);
    T[0] = *reinterpret_cast<const uint4*>(xTn + g.x + cb);
    T[1] = *reinterpret_cast<const uint4*>(xTn + g.y + cb);
    T[2] = *reinterpret_cast<const uint4*>(xTn + g.z + cb);
    T[3] = *reinterpret_cast<const uint4*>(xTn + g.w + cb);
  };

  auto step = [&](uint4 (&T)[4], int kk, int ks0, int buf) {
    short8v wf[2][2];
#pragma unroll
    for (int ks2 = 0; ks2 < 2; ++ks2)
#pragma unroll
      for (int mf = 0; mf < 2; ++mf)
        wf[ks2][mf] = *reinterpret_cast<const short8v*>(
            &wB[(((size_t)((ks0 + ks2) * 16 + (wave << 1) + mf)) * 64 + lane) * 8]);
    float4 w = s_gw[kk][p];
    uint4 r;
    r.x = bilin_pack(T[0].x, T[1].x, T[2].x, T[3].x, w.x, w.y, w.z, w.w);
    r.y = bilin_pack(T[0].y, T[1].y, T[2].y, T[3].y, w.x, w.y, w.z, w.w);
    r.z = bilin_pack(T[0].z, T[1].z, T[2].z, T[3].z, w.x, w.y, w.z, w.w);
    r.w = bilin_pack(T[0].w, T[1].w, T[2].w, T[3].w, w.x, w.y, w.z, w.w);
    *reinterpret_cast<uint4*>(&s_val[buf][p * 64 + ((coct ^ (p & 7)) << 3)]) = r;
    asm volatile("s_waitcnt lgkmcnt(0)" ::: "memory");
    __builtin_amdgcn_s_barrier();
    __builtin_amdgcn_s_setprio(1);
#pragma unroll
    for (int ks2 = 0; ks2 < 2; ++ks2) {
#pragma unroll
      for (int pf = 0; pf < 4; ++pf) {
        int row = (pf << 4) + (lane & 15);
        int g = (ks2 << 2) + (lane >> 4);
        int slot = g ^ (row & 7);
        short8v vf = *reinterpret_cast<const short8v*>(&s_val[buf][row * 64 + slot * 8]);
#pragma unroll
        for (int mf = 0; mf < 2; ++mf)
          acc[mf][pf] = __builtin_amdgcn_mfma_f32_16x16x32_bf16(
              wf[ks2][mf], vf, acc[mf][pf], 0, 0, 0);
      }
    }
    __builtin_amdgcn_s_setprio(0);
  };

  issue(TA, 0, 0);
  for (int kk = 0; kk < 9; ++kk) {
    int ks0 = kk << 3;
    issue(TB, kk, 1);
    step(TA, kk, ks0 + 0, 0);
    issue(TA, kk, 2);
    step(TB, kk, ks0 + 2, 1);
    issue(TB, kk, 3);
    step(TA, kk, ks0 + 4, 0);
    if (kk < 8) issue(TA, kk + 1, 0);
    step(TB, kk, ks0 + 6, 1);
  }

  // ---- epilogue: out NCHW + per-block BN partials ----
#pragma unroll
  for (int mf = 0; mf < 2; ++mf) {
    int ocb = (wave << 5) + (mf << 4) + ((lane >> 4) << 2);
#pragma unroll
    for (int pf = 0; pf < 4; ++pf) {
      int wo = (pf << 4) + (lane & 15);
      float* op = out + (((size_t)(n * 256 + ocb)) * 64 + ho) * 64 + wo;
      float4v a = acc[mf][pf];
      op[0] = a[0];
      op[HW] = a[1];
      op[2 * HW] = a[2];
      op[3 * HW] = a[3];
    }
  }
  float s[2][4], q[2][4];
#pragma unroll
  for (int mf = 0; mf < 2; ++mf)
#pragma unroll
    for (int j = 0; j < 4; ++j) {
      float ss = 0.f, qq = 0.f;
#pragma unroll
      for (int pf = 0; pf < 4; ++pf) {
        float v = acc[mf][pf][j];
        ss += v;
        qq += v * v;
      }
      s[mf][j] = ss;
      q[mf][j] = qq;
    }
#pragma unroll
  for (int o = 1; o < 16; o <<= 1) {
#pragma unroll
    for (int mf = 0; mf < 2; ++mf)
#pragma unroll
      for (int j = 0; j < 4; ++j) {
        s[mf][j] += __shfl_xor(s[mf][j], o);
        q[mf][j] += __shfl_xor(q[mf][j], o);
      }
  }
  if ((lane & 15) == 0) {
#pragma unroll
    for (int mf = 0; mf < 2; ++mf)
#pragma unroll
      for (int j = 0; j < 4; ++j) {
        int oc = (wave << 5) + (mf << 4) + ((lane >> 4) << 2) + j;
        part[(size_t)oc * 512 + bid] = make_float2(s[mf][j], q[mf][j]);
      }
  }
}

__global__ __launch_bounds__(256) void k_stats_fin(const float2* __restrict__ part,
                                                   float2* __restrict__ stats) {
  int oc = blockIdx.x;
  int t = threadIdx.x;
  float2 a = part[(size_t)oc * 512 + t];
  float2 b = part[(size_t)oc * 512 + 256 + t];
  float s = a.x + b.x, q = a.y + b.y;
#pragma unroll
  for (int o = 32; o; o >>= 1) {
    s += __shfl_down(s, o);
    q += __shfl_down(q, o);
  }
  __shared__ float2 wsum[4];
  if ((t & 63) == 0) wsum[t >> 6] = make_float2(s, q);
  __syncthreads();
  if (t == 0) {
    float S = wsum[0].x + wsum[1].x + wsum[2].x + wsum[3].x;
    float Q = wsum[0].y + wsum[1].y + wsum[2].y + wsum[3].y;
    float mean = S / 32768.f;
    float var = Q / 32768.f - mean * mean;
    stats[oc] = make_float2(mean, rsqrtf(var + 1e-5f));
  }
}

// BN+SiLU, XCD-aligned: blocks for image n land on XCD n.
__global__ __launch_bounds__(256) void k_bn_silu(float* __restrict__ out,
                                                 const float2* __restrict__ stats,
                                                 const float* __restrict__ gamma,
                                                 const float* __restrict__ beta) {
  int b = blockIdx.x;
  int nb = (b & 7) * 1024 + (b >> 3);   // image = b&7
  size_t i4 = (size_t)nb * 256 + threadIdx.x;
  int ch = (int)((i4 >> 10) & 255);
  float2 st = stats[ch];
  float g = gamma[ch] * st.y;
  float bb = beta[ch] - st.x * g;
  float4 v = *(float4*)(out + i4 * 4);
  float y0 = v.x * g + bb, y1 = v.y * g + bb, y2 = v.z * g + bb, y3 = v.w * g + bb;
  v.x = y0 / (1.f + expf(-y0));
  v.y = y1 / (1.f + expf(-y1));
  v.z = y2 / (1.f + expf(-y2));
  v.w = y3 / (1.f + expf(-y3));
  *(float4*)(out + i4 * 4) = v;
}

extern "C" void kernel_launch(void* const* d_in, const int* in_sizes, int n_in,
                              void* d_out, int out_size, void* d_ws, size_t ws_size,
                              hipStream_t stream) {
  const float* x      = (const float*)d_in[0];
  const float* w_off  = (const float*)d_in[1];
  const float* b_off  = (const float*)d_in[2];
  const float* w_conv = (const float*)d_in[3];
  const float* gamma  = (const float*)d_in[4];
  const float* beta   = (const float*)d_in[5];
  float* out = (float*)d_out;

  float* ws       = (float*)d_ws;
  ushort* ws_xT   = (ushort*)(ws + 589824);           // [8][4096][256] bf16
  ushort* ws_wB   = (ushort*)(ws + 4784128);          // deform weight frags
  ushort* ws_wOB  = (ushort*)(ws + 5079040);          // offset weight frags
  float2* ws_part = (float2*)(ws + 5115904);          // [256][512] partials
  float2* ws_st   = (float2*)(ws + 5378048);          // [256] stats

  k_tx_prep<<<836, 256, 0, stream>>>(x, w_conv, w_off, ws_xT, ws_wB, ws_wOB);
  k_dfull<<<512, 512, 0, stream>>>(ws_xT, ws_wB, ws_wOB, b_off, out, ws_part);
  k_stats_fin<<<256, 256, 0, stream>>>(ws_part, ws_st);
  k_bn_silu<<<8192, 256, 0, stream>>>(out, ws_st, gamma, beta);
}